// Round 1
// baseline (4743.346 us; speedup 1.0000x reference)
//
#include <hip/hip_runtime.h>
#include <cstddef>

// ---------------------------------------------------------------------------
// EGNN layer, fp32 end-to-end (mod-1.0 wrap safety requires fp32 precision).
//
// Decomposition:
//   K1 node_pre : H1a = h@W1[:, :64]^T + b1 ; H1b = h@W1[:,64:128]^T   [N,64]x2
//   K2 edge     : t1 = silu(H1a[src]+H1b[dst]+r*W1c)                   [E,64]
//                 m  = silu(t1@W2^T + b2)      -> atomic m_sum[src]    [E,64]
//                 p  = silu(m@P1^T + pb1); w = p.P2 + pb2              [E]
//                 x_ij = x[src] + e_ij*w       -> atomic x_sum[src], cnt[src]
//   K3 gru      : m_i = m_sum/cnt ; GRU ; x outputs
// ---------------------------------------------------------------------------

__device__ __forceinline__ float silu_f(float v) {
    return v / (1.0f + expf(-v));
}
__device__ __forceinline__ float sigmoid_f(float v) {
    return 1.0f / (1.0f + expf(-v));
}

// ---------------- K1: per-node precompute -----------------------------------
__global__ __launch_bounds__(256) void node_pre_kernel(
    const float* __restrict__ h, const float* __restrict__ W1,
    const float* __restrict__ b1,
    float* __restrict__ H1a, float* __restrict__ H1b, int N)
{
    __shared__ float sh[16][68];
    int n0 = blockIdx.x * 16;
    int tx = threadIdx.x;
    for (int i = tx; i < 16 * 64; i += 256) {
        int ln = i >> 6, k = i & 63;
        int n = n0 + ln;
        sh[ln][k] = (n < N) ? h[(size_t)n * 64 + k] : 0.0f;
    }
    __syncthreads();
    int ln = tx >> 4;      // node in tile
    int lane = tx & 15;    // 8 outputs each over 128 outputs
    int n = n0 + ln;
    if (n >= N) return;
    #pragma unroll
    for (int oq = 0; oq < 8; ++oq) {
        int o = lane * 8 + oq;   // 0..127
        const float* wrow = (o < 64) ? (W1 + o * 129) : (W1 + (o - 64) * 129 + 64);
        float acc = (o < 64) ? b1[o] : 0.0f;
        #pragma unroll 8
        for (int k = 0; k < 64; ++k) acc += sh[ln][k] * wrow[k];
        if (o < 64) H1a[(size_t)n * 64 + o] = acc;
        else        H1b[(size_t)n * 64 + (o - 64)] = acc;
    }
}

// ---------------- K2: edge pipeline ------------------------------------------
// One tile = 64 edges. Activations stored transposed in LDS: sA[k][e], pad 68.
// GEMM micro-tile: 256 threads, each 4 edges x 4 feats.

__device__ __forceinline__ void tile_gemm_silu(
    const float (*__restrict__ Ain)[68],   // [k][e]  (64x64 live)
    const float (*__restrict__ WT)[64],    // [k][f]  WT[k][f] = W[f][k]
    const float* __restrict__ bias,        // [64]
    float (*__restrict__ Bout)[68],        // [f][e]
    float out[4][4],                       // out[q][c] = value(edge 4te+q, f 4tf+c)
    int tx)
{
    int tf = tx & 15, te = tx >> 4;
    float acc[4][4];
    #pragma unroll
    for (int q = 0; q < 4; ++q)
        acc[q][0] = acc[q][1] = acc[q][2] = acc[q][3] = 0.0f;

    #pragma unroll
    for (int k = 0; k < 64; k += 4) {
        float4 av[4], wv[4];
        #pragma unroll
        for (int kk = 0; kk < 4; ++kk) av[kk] = *(const float4*)&Ain[k + kk][4 * te];
        #pragma unroll
        for (int kk = 0; kk < 4; ++kk) wv[kk] = *(const float4*)&WT[k + kk][4 * tf];
        #pragma unroll
        for (int kk = 0; kk < 4; ++kk) {
            float a0 = av[kk].x, a1 = av[kk].y, a2 = av[kk].z, a3 = av[kk].w;
            float w0 = wv[kk].x, w1 = wv[kk].y, w2 = wv[kk].z, w3 = wv[kk].w;
            acc[0][0] += a0 * w0; acc[0][1] += a0 * w1; acc[0][2] += a0 * w2; acc[0][3] += a0 * w3;
            acc[1][0] += a1 * w0; acc[1][1] += a1 * w1; acc[1][2] += a1 * w2; acc[1][3] += a1 * w3;
            acc[2][0] += a2 * w0; acc[2][1] += a2 * w1; acc[2][2] += a2 * w2; acc[2][3] += a2 * w3;
            acc[3][0] += a3 * w0; acc[3][1] += a3 * w1; acc[3][2] += a3 * w2; acc[3][3] += a3 * w3;
        }
    }
    // bias + silu, write transposed [f][e] via float4 along e
    #pragma unroll
    for (int c = 0; c < 4; ++c) {
        float b = bias[4 * tf + c];
        float4 m4;
        m4.x = silu_f(acc[0][c] + b);
        m4.y = silu_f(acc[1][c] + b);
        m4.z = silu_f(acc[2][c] + b);
        m4.w = silu_f(acc[3][c] + b);
        *(float4*)&Bout[4 * tf + c][4 * te] = m4;
        out[0][c] = m4.x; out[1][c] = m4.y; out[2][c] = m4.z; out[3][c] = m4.w;
    }
}

__global__ __launch_bounds__(256, 2) void edge_kernel(
    const float* __restrict__ H1a, const float* __restrict__ H1b,
    const float* __restrict__ x,
    const float* __restrict__ r_ij, const float* __restrict__ e_ij,
    const int* __restrict__ src, const int* __restrict__ dst,
    const float* __restrict__ W1, const float* __restrict__ W2,
    const float* __restrict__ b2, const float* __restrict__ P1,
    const float* __restrict__ pb1, const float* __restrict__ P2,
    const float* __restrict__ pb2,
    float* __restrict__ m_sum, float* __restrict__ x_sum,
    int* __restrict__ cnt, int E)
{
    __shared__ float sW2T[64][64];   // [k][f]
    __shared__ float sP1T[64][64];
    __shared__ float sA[64][68];     // transposed activations [k][e]
    __shared__ float sB[64][68];
    __shared__ float sP2[64], sb2[64], spb1[64], sW1c[64];
    __shared__ int   sSrc[64];
    __shared__ float spb2s;

    int tx = threadIdx.x;
    for (int i = tx; i < 64 * 64; i += 256) {
        int f = i >> 6, k = i & 63;
        sW2T[k][f] = W2[f * 64 + k];
        sP1T[k][f] = P1[f * 64 + k];
    }
    if (tx < 64) {
        sP2[tx]  = P2[tx];
        sb2[tx]  = b2[tx];
        spb1[tx] = pb1[tx];
        sW1c[tx] = W1[tx * 129 + 128];
    }
    if (tx == 0) spb2s = pb2[0];
    __syncthreads();

    int ntile = E >> 6;
    for (int t = blockIdx.x; t < ntile; t += gridDim.x) {
        int e0 = t << 6;

        // ---- phase 0: gather + first layer -> sA[f][e] = silu(t1)
        {
            int le = tx >> 2;      // edge in tile
            int j  = tx & 3;       // 16-feature quarter
            int e  = e0 + le;
            int s = src[e], d = dst[e];
            float r = r_ij[e];
            if (j == 0) sSrc[le] = s;
            const float* pa = H1a + (size_t)s * 64 + j * 16;
            const float* pb = H1b + (size_t)d * 64 + j * 16;
            #pragma unroll
            for (int q = 0; q < 4; ++q) {
                float4 va = *(const float4*)(pa + 4 * q);
                float4 vb = *(const float4*)(pb + 4 * q);
                int f = j * 16 + 4 * q;
                sA[f + 0][le] = silu_f(va.x + vb.x + r * sW1c[f + 0]);
                sA[f + 1][le] = silu_f(va.y + vb.y + r * sW1c[f + 1]);
                sA[f + 2][le] = silu_f(va.z + vb.z + r * sW1c[f + 2]);
                sA[f + 3][le] = silu_f(va.w + vb.w + r * sW1c[f + 3]);
            }
        }
        __syncthreads();

        // ---- phase 1: m = silu(A@W2^T + b2) -> sB ; atomic m_sum[src]
        {
            float mv[4][4];
            tile_gemm_silu(sA, sW2T, sb2, sB, mv, tx);
            int tf = tx & 15, te = tx >> 4;
            #pragma unroll
            for (int q = 0; q < 4; ++q) {
                int s = sSrc[4 * te + q];
                float* mp = m_sum + (size_t)s * 64 + 4 * tf;
                atomicAdd(mp + 0, mv[q][0]);
                atomicAdd(mp + 1, mv[q][1]);
                atomicAdd(mp + 2, mv[q][2]);
                atomicAdd(mp + 3, mv[q][3]);
            }
        }
        __syncthreads();

        // ---- phase 2: p = silu(m@P1^T + pb1) -> sA
        {
            float pv[4][4];
            tile_gemm_silu(sB, sP1T, spb1, sA, pv, tx);
        }
        __syncthreads();

        // ---- phase 3: w = p.P2 + pb2 ; x scatter
        {
            int le = tx >> 2, j = tx & 3;
            int e = e0 + le;
            float part = 0.0f;
            #pragma unroll
            for (int ff = 0; ff < 16; ++ff) {
                int f = j * 16 + ff;
                part += sA[f][le] * sP2[f];
            }
            part += __shfl_xor(part, 1);
            part += __shfl_xor(part, 2);
            if (j == 0) {
                float w = part + spb2s;
                int s = sSrc[le];
                float ex = e_ij[3 * (size_t)e + 0];
                float ey = e_ij[3 * (size_t)e + 1];
                float ez = e_ij[3 * (size_t)e + 2];
                float x0 = x[3 * (size_t)s + 0];
                float x1 = x[3 * (size_t)s + 1];
                float x2 = x[3 * (size_t)s + 2];
                atomicAdd(&x_sum[3 * (size_t)s + 0], x0 + ex * w);
                atomicAdd(&x_sum[3 * (size_t)s + 1], x1 + ey * w);
                atomicAdd(&x_sum[3 * (size_t)s + 2], x2 + ez * w);
                atomicAdd(&cnt[s], 1);
            }
        }
        __syncthreads();
    }
}

// ---------------- K3: GRU + x epilogue ---------------------------------------
__global__ __launch_bounds__(256) void gru_kernel(
    const float* __restrict__ h, const float* __restrict__ x,
    const float* __restrict__ m_sum, const float* __restrict__ x_sum,
    const int* __restrict__ cnt,
    const float* __restrict__ W_ih, const float* __restrict__ W_hh,
    const float* __restrict__ b_ih, const float* __restrict__ b_hh,
    float* __restrict__ out_xmod, float* __restrict__ out_xdiff,
    float* __restrict__ out_h, int N)
{
    __shared__ float smi[16][68];
    __shared__ float shv[16][68];
    __shared__ float sgi[16][196];
    __shared__ float sgh[16][196];
    int n0 = blockIdx.x * 16;
    int tx = threadIdx.x;
    for (int i = tx; i < 16 * 64; i += 256) {
        int ln = i >> 6, f = i & 63;
        int n = n0 + ln;
        if (n < N) {
            float c = (float)max(cnt[n], 1);
            smi[ln][f] = m_sum[(size_t)n * 64 + f] / c;
            shv[ln][f] = h[(size_t)n * 64 + f];
        } else { smi[ln][f] = 0.0f; shv[ln][f] = 0.0f; }
    }
    __syncthreads();
    {
        int ln = tx >> 4, lane = tx & 15;
        int n = n0 + ln;
        if (n < N) {
            float ai[12], ah[12];
            #pragma unroll
            for (int oq = 0; oq < 12; ++oq) {
                int f = lane * 12 + oq;
                ai[oq] = b_ih[f];
                ah[oq] = b_hh[f];
            }
            #pragma unroll 4
            for (int k4 = 0; k4 < 16; ++k4) {
                float4 mi4 = *(const float4*)&smi[ln][4 * k4];
                float4 hv4 = *(const float4*)&shv[ln][4 * k4];
                #pragma unroll
                for (int oq = 0; oq < 12; ++oq) {
                    int f = lane * 12 + oq;
                    const float* wi = W_ih + (size_t)f * 64 + 4 * k4;
                    const float* wh = W_hh + (size_t)f * 64 + 4 * k4;
                    ai[oq] += mi4.x * wi[0] + mi4.y * wi[1] + mi4.z * wi[2] + mi4.w * wi[3];
                    ah[oq] += hv4.x * wh[0] + hv4.y * wh[1] + hv4.z * wh[2] + hv4.w * wh[3];
                }
            }
            #pragma unroll
            for (int oq = 0; oq < 12; ++oq) {
                int f = lane * 12 + oq;
                sgi[ln][f] = ai[oq];
                sgh[ln][f] = ah[oq];
            }
        }
    }
    __syncthreads();
    {
        int ln = tx >> 4, lane = tx & 15;
        int n = n0 + ln;
        if (n < N) {
            #pragma unroll
            for (int q = 0; q < 4; ++q) {
                int f = lane * 4 + q;
                float r  = sigmoid_f(sgi[ln][f]       + sgh[ln][f]);
                float z  = sigmoid_f(sgi[ln][64 + f]  + sgh[ln][64 + f]);
                float nn = tanhf   (sgi[ln][128 + f] + r * sgh[ln][128 + f]);
                out_h[(size_t)n * 64 + f] = (1.0f - z) * nn + z * shv[ln][f];
            }
        }
        if (tx < 16) {
            int n2 = n0 + tx;
            if (n2 < N) {
                float c = (float)max(cnt[n2], 1);
                #pragma unroll
                for (int d3 = 0; d3 < 3; ++d3) {
                    float xp = x_sum[(size_t)n2 * 3 + d3] / c;
                    out_xmod [(size_t)n2 * 3 + d3] = xp - floorf(xp);
                    out_xdiff[(size_t)n2 * 3 + d3] = xp - x[(size_t)n2 * 3 + d3];
                }
            }
        }
    }
}

// ---------------------------------------------------------------------------
extern "C" void kernel_launch(void* const* d_in, const int* in_sizes, int n_in,
                              void* d_out, int out_size, void* d_ws, size_t ws_size,
                              hipStream_t stream)
{
    const float* h    = (const float*)d_in[0];
    const float* x    = (const float*)d_in[1];
    const float* r_ij = (const float*)d_in[2];
    const float* e_ij = (const float*)d_in[3];
    const int*   src  = (const int*)d_in[4];
    const int*   dst  = (const int*)d_in[5];
    const float* W1   = (const float*)d_in[6];
    const float* b1   = (const float*)d_in[7];
    const float* W2   = (const float*)d_in[8];
    const float* b2   = (const float*)d_in[9];
    const float* P1   = (const float*)d_in[10];
    const float* pb1  = (const float*)d_in[11];
    const float* P2   = (const float*)d_in[12];
    const float* pb2  = (const float*)d_in[13];
    const float* W_ih = (const float*)d_in[14];
    const float* W_hh = (const float*)d_in[15];
    const float* b_ih = (const float*)d_in[16];
    const float* b_hh = (const float*)d_in[17];

    int N = in_sizes[0] / 64;
    int E = in_sizes[2];

    float* ws    = (float*)d_ws;
    float* H1a   = ws;                          // N*64
    float* H1b   = H1a + (size_t)N * 64;        // N*64
    float* m_sum = H1b + (size_t)N * 64;        // N*64
    float* x_sum = m_sum + (size_t)N * 64;      // N*3
    int*   cnt   = (int*)(x_sum + (size_t)N * 3); // N

    size_t zero_bytes = ((size_t)N * 64 + (size_t)N * 3 + (size_t)N) * sizeof(float);
    hipMemsetAsync(m_sum, 0, zero_bytes, stream);

    int nwg_nodes = (N + 15) / 16;
    node_pre_kernel<<<nwg_nodes, 256, 0, stream>>>(h, W1, b1, H1a, H1b, N);

    int ntile = E >> 6;
    int nwg_e = ntile < 2048 ? ntile : 2048;
    edge_kernel<<<nwg_e, 256, 0, stream>>>(H1a, H1b, x, r_ij, e_ij, src, dst,
        W1, W2, b2, P1, pb1, P2, pb2, m_sum, x_sum, cnt, E);

    float* out_xmod  = (float*)d_out;
    float* out_xdiff = out_xmod + (size_t)N * 3;
    float* out_h     = out_xdiff + (size_t)N * 3;
    gru_kernel<<<nwg_nodes, 256, 0, stream>>>(h, x, m_sum, x_sum, cnt,
        W_ih, W_hh, b_ih, b_hh, out_xmod, out_xdiff, out_h, N);
}